// Round 8
// baseline (81.350 us; speedup 1.0000x reference)
//
#include <hip/hip_runtime.h>
#include <hip/hip_bf16.h>

// Problem constants (EdgeQProj): B=64, N=64, E=512, OBJ_DIM=2048, Q_DIM=1024,
// HID=512, KS=8. M_edges = B*E = 32768.
//
// Pipeline (identity: edge_logit[m] = P[b,src]+P[b,dst],
//           P[b] = relu(node_feats@W_obj+b) @ q_e[b] * inv_norm[b]):
//   cvt_a  : node_feats fp32 -> bf16 (one pass, memory-floor)
//   cvt_bt : W_obj -> W_T bf16 transposed
//   gemm1  : node_h = relu(A@W^T + b)   (m97-style global_load_lds staging)
//   gemm2  : q partials (fused fp32->bf16 MFMA, single-pass W_q)
//   tail_k : per-batch fused reduce+bias+relu -> norms -> P-MFMA -> edges

using bf16x8 = __attribute__((ext_vector_type(8))) __bf16;
using f32x4  = __attribute__((ext_vector_type(4))) float;

__device__ __forceinline__ unsigned short f2bf(float f) {
    unsigned int u = __float_as_uint(f);
    unsigned int r = (u + 0x7FFFu + ((u >> 16) & 1u)) >> 16;  // RNE
    return (unsigned short)r;
}

__device__ __forceinline__ bf16x8 pk8(f32x4 a, f32x4 b) {
    union { unsigned short us[8]; bf16x8 v; } r;
    r.us[0] = f2bf(a[0]); r.us[1] = f2bf(a[1]); r.us[2] = f2bf(a[2]); r.us[3] = f2bf(a[3]);
    r.us[4] = f2bf(b[0]); r.us[5] = f2bf(b[1]); r.us[6] = f2bf(b[2]); r.us[7] = f2bf(b[3]);
    return r.v;
}

// async global->LDS, 16B/lane: LDS dest = wave-uniform base + lane*16;
// global src is per-lane. __syncthreads() drains vmcnt before s_barrier.
__device__ __forceinline__ void gl_lds16(const void* g, void* l) {
    __builtin_amdgcn_global_load_lds(
        (const __attribute__((address_space(1))) unsigned int*)g,
        (__attribute__((address_space(3))) unsigned int*)l,
        16, 0, 0);
}

// ---------------------------------------------------------------------------
// 1) node_feats fp32 [4096][2048] -> bf16 (workspace), one pass
__global__ __launch_bounds__(256) void cvt_a(const float* __restrict__ in,
                                             unsigned short* __restrict__ out) {
    int tid = blockIdx.x * 256 + threadIdx.x;          // 2048*256 = 524288
    for (int p = tid; p < 2097152; p += 524288) {      // 8388608/4 float4s
        float4 v = *(const float4*)(in + (size_t)p * 4);
        ushort4 o;
        o.x = f2bf(v.x); o.y = f2bf(v.y); o.z = f2bf(v.z); o.w = f2bf(v.w);
        *(ushort4*)(out + (size_t)p * 4) = o;
    }
}

// ---------------------------------------------------------------------------
// 2) W_obj fp32 [2048][512] -> W_T bf16 [512][2048]  (tiled transpose)
__global__ __launch_bounds__(256) void cvt_bt(const float* __restrict__ W,
                                              unsigned short* __restrict__ WT) {
    __shared__ float lds[32][33];
    int k0 = blockIdx.x * 32, n0 = blockIdx.y * 32;
    int tx = threadIdx.x & 31, ty = threadIdx.x >> 5;  // ty 0..7
#pragma unroll
    for (int j = 0; j < 4; ++j)
        lds[ty + j * 8][tx] = W[(size_t)(k0 + ty + j * 8) * 512 + n0 + tx];
    __syncthreads();
#pragma unroll
    for (int j = 0; j < 4; ++j)
        WT[(size_t)(n0 + ty + j * 8) * 2048 + k0 + tx] = f2bf(lds[tx][ty + j * 8]);
}

// ---------------------------------------------------------------------------
// 3) GEMM1 (m97-style): node_h[4096][512](fp32) = relu(A_bf16 @ W_T^T + b).
//    BM=128 BN=64 BK=128, 512 thr (8 waves 4x2). LINEAR LDS (required by
//    global_load_lds), 6 gl_lds16 + 16 MFMAs per wave per 2-barrier step,
//    16 steps. 48KB LDS -> 3 blocks/CU. The 16-way ds_read conflict of the
//    linear layout is not critical-path at 2-phase (m228d/m233 regime gate).
__global__ __launch_bounds__(512) void gemm1(const unsigned short* __restrict__ A,
                                             const unsigned short* __restrict__ BT,
                                             const float* __restrict__ bias,
                                             float* __restrict__ C) {
    __shared__ __align__(16) unsigned short Asm[128 * 128];
    __shared__ __align__(16) unsigned short Bsm[64 * 128];

    // XCD swizzle: grid 256 (%8==0, bijective). per-XCD: 4 A m-panels
    // (2.1MB bf16) + full B (2MB) ~ L2-resident.
    int bid = blockIdx.x;
    int swz = (bid & 7) * 32 + (bid >> 3);
    int by = swz >> 3, bx = swz & 7;
    int m0 = by * 128, n0 = bx * 64;

    int t = threadIdx.x;
    int lane = t & 63, w = t >> 6;
    int wm = w >> 1, wn = w & 1;              // wave grid 4x2
    int l15 = lane & 15, l16 = lane >> 4;

    // staging: 1KB wave-chunk = 4 rows x 128 cols bf16 (256B/row);
    // lane l covers row l>>4, cols (l&15)*8 -> byte off = l*16 (linear).
    int srow = lane >> 4, scol = (lane & 15) * 8;
    const unsigned short* aG = A  + (size_t)(m0 + w * 16 + srow) * 2048 + scol;
    const unsigned short* bG = BT + (size_t)(n0 + w * 8 + srow) * 2048 + scol;
    unsigned short* aL = Asm + (w * 16) * 128;   // wave-uniform
    unsigned short* bL = Bsm + (w * 8) * 128;

    f32x4 acc[2][2];
#pragma unroll
    for (int i = 0; i < 2; ++i)
#pragma unroll
        for (int j = 0; j < 2; ++j) acc[i][j] = (f32x4){0.f, 0.f, 0.f, 0.f};

    for (int s = 0; s < 16; ++s) {
        int k0 = s * 128;
        // ---- async stage: A 4 chunks/wave, B 2 chunks/wave ----
#pragma unroll
        for (int i = 0; i < 4; ++i)
            gl_lds16(aG + (size_t)(i * 4) * 2048 + k0, aL + (i * 4) * 128);
#pragma unroll
        for (int i = 0; i < 2; ++i)
            gl_lds16(bG + (size_t)(i * 4) * 2048 + k0, bL + (i * 4) * 128);
        __syncthreads();                       // vmcnt drain + barrier

        // ---- compute: 4 ksubs x (2x2) MFMAs ----
#pragma unroll
        for (int ks = 0; ks < 4; ++ks) {
            const unsigned short* ab = Asm + (size_t)(wm * 32) * 128 + ks * 32 + l16 * 8;
            const unsigned short* bb = Bsm + (size_t)(wn * 32) * 128 + ks * 32 + l16 * 8;
            bf16x8 a0 = *(const bf16x8*)(ab + (size_t)l15 * 128);
            bf16x8 a1 = *(const bf16x8*)(ab + (size_t)(16 + l15) * 128);
            bf16x8 b0 = *(const bf16x8*)(bb + (size_t)l15 * 128);
            bf16x8 b1 = *(const bf16x8*)(bb + (size_t)(16 + l15) * 128);
            acc[0][0] = __builtin_amdgcn_mfma_f32_16x16x32_bf16(a0, b0, acc[0][0], 0, 0, 0);
            acc[0][1] = __builtin_amdgcn_mfma_f32_16x16x32_bf16(a0, b1, acc[0][1], 0, 0, 0);
            acc[1][0] = __builtin_amdgcn_mfma_f32_16x16x32_bf16(a1, b0, acc[1][0], 0, 0, 0);
            acc[1][1] = __builtin_amdgcn_mfma_f32_16x16x32_bf16(a1, b1, acc[1][1], 0, 0, 0);
        }
        __syncthreads();                       // readers done before re-stage
    }

    // epilogue: bias + relu -> fp32; D layout col=lane&15, row=(lane>>4)*4+j
#pragma unroll
    for (int fm = 0; fm < 2; ++fm)
#pragma unroll
        for (int fn = 0; fn < 2; ++fn) {
            int col = n0 + wn * 32 + fn * 16 + l15;
            float bv = bias[col];
#pragma unroll
            for (int j = 0; j < 4; ++j) {
                int row = m0 + wm * 32 + fm * 16 + l16 * 4 + j;
                float v = acc[fm][fn][j] + bv;
                C[(size_t)row * 512 + col] = v > 0.f ? v : 0.f;
            }
        }
}

// ---------------------------------------------------------------------------
// 4) GEMM2 (fused fp32->bf16 MFMA, single-pass W_q):
//    part[z][64][4096] = q[64][k0:k0+128] @ W_q[k0:k0+128][c0:c0+128]
//    grid (32 colblocks, 8 ksplits) = 256 blocks x 256 thr (4 waves).
#define LDK2 136
__global__ __launch_bounds__(256) void gemm2(const float* __restrict__ qf,
                                             const float* __restrict__ Wq,
                                             float* __restrict__ part) {
    __shared__ __align__(16) unsigned short Asm[64][LDK2];   // q tile  [m][k]
    __shared__ __align__(16) unsigned short Bsm[128][LDK2];  // W tile  [c][k]

    int t = threadIdx.x;
    int lane = t & 63, w = t >> 6;          // 4 waves, wave owns 32 cols
    int l15 = lane & 15, l16 = lane >> 4;
    int c0 = blockIdx.x * 128;
    int k0 = blockIdx.y * 128;

    // ---- stage A: q[64][k0:k0+128] fp32 -> bf16 ----
#pragma unroll
    for (int j = 0; j < 4; ++j) {
        int g = t + j * 256;                 // 1024 chunks of 8k
        int row = g >> 4, kc = g & 15;
        const float* src = qf + (size_t)row * 1024 + k0 + kc * 8;
        f32x4 v0 = *(const f32x4*)(src);
        f32x4 v1 = *(const f32x4*)(src + 4);
        *(bf16x8*)(&Asm[row][kc * 8]) = pk8(v0, v1);
    }
    // ---- stage B: W_q[k0:k0+128][c0:c0+128] fp32 -> bf16, transposed ----
#pragma unroll
    for (int j = 0; j < 2; ++j) {
        int g = t + j * 256;                 // 512 units of 8k x 4c
        int kg = g >> 5, cg = g & 31;
        f32x4 wv[8];
#pragma unroll
        for (int kk = 0; kk < 8; ++kk)
            wv[kk] = *(const f32x4*)(Wq + (size_t)(k0 + kg * 8 + kk) * 4096 + c0 + cg * 4);
#pragma unroll
        for (int cc = 0; cc < 4; ++cc) {
            union { unsigned short us[8]; uint4 u4; } p;
#pragma unroll
            for (int kk = 0; kk < 8; ++kk) p.us[kk] = f2bf(wv[kk][cc]);
            *(uint4*)(&Bsm[cg * 4 + cc][kg * 8]) = p.u4;
        }
    }
    __syncthreads();

    // ---- MFMA: wave w covers cols [w*32, w*32+32); 4m x 2n x 4k frags ----
    f32x4 acc[4][2];
#pragma unroll
    for (int i = 0; i < 4; ++i)
#pragma unroll
        for (int j = 0; j < 2; ++j) acc[i][j] = (f32x4){0.f, 0.f, 0.f, 0.f};

#pragma unroll
    for (int ks = 0; ks < 4; ++ks) {
        bf16x8 bfr[2];
#pragma unroll
        for (int jn = 0; jn < 2; ++jn)
            bfr[jn] = *(const bf16x8*)(&Bsm[w * 32 + jn * 16 + l15][ks * 32 + l16 * 8]);
#pragma unroll
        for (int i = 0; i < 4; ++i) {
            bf16x8 afr = *(const bf16x8*)(&Asm[i * 16 + l15][ks * 32 + l16 * 8]);
            acc[i][0] = __builtin_amdgcn_mfma_f32_16x16x32_bf16(afr, bfr[0], acc[i][0], 0, 0, 0);
            acc[i][1] = __builtin_amdgcn_mfma_f32_16x16x32_bf16(afr, bfr[1], acc[i][1], 0, 0, 0);
        }
    }

    // ---- write partials ----
    float* pz = part + (size_t)blockIdx.y * 262144;
#pragma unroll
    for (int i = 0; i < 4; ++i)
#pragma unroll
        for (int jn = 0; jn < 2; ++jn) {
            int col = c0 + w * 32 + jn * 16 + l15;
#pragma unroll
            for (int j = 0; j < 4; ++j) {
                int row = i * 16 + l16 * 4 + j;
                pz[(size_t)row * 4096 + col] = acc[i][jn][j];
            }
        }
}

// ---------------------------------------------------------------------------
// 5) tail_k: one block per batch b (64 blocks x 256 thr = 4 waves).
//    Phase 1: q_h[b][*] = relu(sum_z part[z][b][*] + b_q)      -> LDS qs
//    Phase 2: inv_norm[b][k] = 1/sqrt(sum_h qs[h*8+k]^2)       -> LDS inv
//    Phase 3: P[n][k] = (node_h[b] @ q_e[b]) * inv             -> LDS Pl
//    Phase 4: out[m] = Pl[src] + Pl[dst] for the 512 edges of batch b
__global__ __launch_bounds__(256) void tail_k(const float* __restrict__ part,
                                              const float* __restrict__ bq,
                                              const float* __restrict__ node_h,
                                              const int* __restrict__ idxs,
                                              float* __restrict__ out) {
    __shared__ float qs[4096];
    __shared__ float red[4][8];
    __shared__ float inv[8];
    __shared__ float Pl[64][8];

    int b = blockIdx.x, t = threadIdx.x;
    int lane = t & 63, w = t >> 6;
    int l15 = lane & 15, l16 = lane >> 4;

    // ---- phase 1: reduce k-split partials + bias + relu ----
#pragma unroll
    for (int j = 0; j < 4; ++j) {
        int c = j * 1024 + t * 4;
        f32x4 a = (f32x4){0.f, 0.f, 0.f, 0.f};
#pragma unroll
        for (int z = 0; z < 8; ++z)
            a += *(const f32x4*)(part + (size_t)z * 262144 + (size_t)b * 4096 + c);
        f32x4 bb = *(const f32x4*)(bq + c);
#pragma unroll
        for (int i = 0; i < 4; ++i) {
            float v = a[i] + bb[i];
            a[i] = v > 0.f ? v : 0.f;
        }
        *(f32x4*)(&qs[c]) = a;
    }
    __syncthreads();

    // ---- phase 2: per-k norms ----
    {
        const float* row = qs + t * 16;
        float sq[8] = {0.f, 0.f, 0.f, 0.f, 0.f, 0.f, 0.f, 0.f};
#pragma unroll
        for (int j = 0; j < 4; ++j) {
            f32x4 v = *(const f32x4*)(row + j * 4);
            sq[(j * 4 + 0) & 7] += v[0] * v[0];
            sq[(j * 4 + 1) & 7] += v[1] * v[1];
            sq[(j * 4 + 2) & 7] += v[2] * v[2];
            sq[(j * 4 + 3) & 7] += v[3] * v[3];
        }
#pragma unroll
        for (int k = 0; k < 8; ++k) {
            float v = sq[k];
            v += __shfl_xor(v, 1);  v += __shfl_xor(v, 2);  v += __shfl_xor(v, 4);
            v += __shfl_xor(v, 8);  v += __shfl_xor(v, 16); v += __shfl_xor(v, 32);
            sq[k] = v;
        }
        if (lane == 0) {
#pragma unroll
            for (int k = 0; k < 8; ++k) red[w][k] = sq[k];
        }
    }
    __syncthreads();
    if (t < 8) {
        float s = red[0][t] + red[1][t] + red[2][t] + red[3][t];
        inv[t] = 1.0f / sqrtf(s);
    }
    __syncthreads();

    // ---- phase 3: P = (node_h[b] @ q_e) * inv  (MFMA 16x16x32, N=8 used) --
    {
        bool active = l15 < 8;
        float invv = active ? inv[l15] : 0.f;
        const float* arow = node_h + (size_t)(b * 64 + w * 16 + l15) * 512 + l16 * 8;
        f32x4 acc = (f32x4){0.f, 0.f, 0.f, 0.f};
#pragma unroll
        for (int kt = 0; kt < 16; ++kt) {
            f32x4 v0 = *(const f32x4*)(arow + kt * 32);
            f32x4 v1 = *(const f32x4*)(arow + kt * 32 + 4);
            bf16x8 af = pk8(v0, v1);
            union { unsigned short us[8]; bf16x8 v; } bqf;
#pragma unroll
            for (int i = 0; i < 8; ++i)
                bqf.us[i] = active ? f2bf(qs[kt * 256 + (l16 * 8 + i) * 8 + l15]) : 0;
            acc = __builtin_amdgcn_mfma_f32_16x16x32_bf16(af, bqf.v, acc, 0, 0, 0);
        }
        if (active) {
#pragma unroll
            for (int j = 0; j < 4; ++j)
                Pl[w * 16 + l16 * 4 + j][l15] = acc[j] * invv;
        }
    }
    __syncthreads();

    // ---- phase 4: 512 edges of batch b, 2 per thread ----
#pragma unroll
    for (int e = 0; e < 2; ++e) {
        int m = b * 512 + e * 256 + t;
        int idx = idxs[m];
        int r = idx & 4095;
        int src = r >> 6, dst = r & 63;
        f32x4 o0 = *(const f32x4*)(&Pl[src][0]) + *(const f32x4*)(&Pl[dst][0]);
        f32x4 o1 = *(const f32x4*)(&Pl[src][4]) + *(const f32x4*)(&Pl[dst][4]);
        *(f32x4*)(out + (size_t)m * 8)     = o0;
        *(f32x4*)(out + (size_t)m * 8 + 4) = o1;
    }
}

// ---------------------------------------------------------------------------
extern "C" void kernel_launch(void* const* d_in, const int* in_sizes, int n_in,
                              void* d_out, int out_size, void* d_ws, size_t ws_size,
                              hipStream_t stream) {
    const float* node_feats = (const float*)d_in[0];  // [64][64][2048]
    const float* q_feats    = (const float*)d_in[1];  // [64][1024]
    const int*   indexes    = (const int*)d_in[2];    // [32768]
    const float* W_obj      = (const float*)d_in[3];  // [2048][512]
    const float* b_obj      = (const float*)d_in[4];  // [512]
    const float* W_q        = (const float*)d_in[5];  // [1024][4096]
    const float* b_q        = (const float*)d_in[6];  // [4096]
    float* out = (float*)d_out;                       // [32768][8]

    char* ws = (char*)d_ws;
    unsigned short* A_bf16 = (unsigned short*)(ws + 0);        // 16.78MB
    unsigned short* W_T    = (unsigned short*)(ws + 16777216); // 2.10MB
    float* node_h          = (float*)(ws + 18874368);          // 8.39MB fp32
    float* part            = (float*)(ws + 0);                 // aliases A_bf16
                                                               // (gemm2 after gemm1)

    cvt_a<<<2048, 256, 0, stream>>>(node_feats, A_bf16);
    cvt_bt<<<dim3(64, 16), 256, 0, stream>>>(W_obj, W_T);
    gemm1<<<256, 512, 0, stream>>>(A_bf16, W_T, b_obj, node_h);
    gemm2<<<dim3(32, 8), 256, 0, stream>>>(q_feats, W_q, part);
    tail_k<<<64, 256, 0, stream>>>(part, b_q, node_h, indexes, out);
}

// Round 9
// 70.577 us; speedup vs baseline: 1.1526x; 1.1526x over previous
//
#include <hip/hip_runtime.h>
#include <hip/hip_bf16.h>

// Problem constants (EdgeQProj): B=64, N=64, E=512, OBJ_DIM=2048, Q_DIM=1024,
// HID=512, KS=8. M_edges = B*E = 32768.
//
// Pipeline (identity: edge_logit[m] = P[b,src]+P[b,dst],
//           P[b] = relu(node_feats@W_obj+b) @ q_e[b] * inv_norm[b]):
//   cvt_a  : node_feats fp32 -> bf16 (one pass, memory-floor)
//   cvt_bt : W_obj -> W_T bf16 transposed
//   gemm1  : node_h = relu(A@W^T + b)  (gl_lds + DOUBLE-BUFFER T3 pipeline)
//   gemm2  : q partials (fused fp32->bf16 MFMA, single-pass W_q)
//   tail_k : per-batch fused reduce+bias+relu -> norms -> P-MFMA -> edges

using bf16x8 = __attribute__((ext_vector_type(8))) __bf16;
using f32x4  = __attribute__((ext_vector_type(4))) float;

__device__ __forceinline__ unsigned short f2bf(float f) {
    unsigned int u = __float_as_uint(f);
    unsigned int r = (u + 0x7FFFu + ((u >> 16) & 1u)) >> 16;  // RNE
    return (unsigned short)r;
}

__device__ __forceinline__ bf16x8 pk8(f32x4 a, f32x4 b) {
    union { unsigned short us[8]; bf16x8 v; } r;
    r.us[0] = f2bf(a[0]); r.us[1] = f2bf(a[1]); r.us[2] = f2bf(a[2]); r.us[3] = f2bf(a[3]);
    r.us[4] = f2bf(b[0]); r.us[5] = f2bf(b[1]); r.us[6] = f2bf(b[2]); r.us[7] = f2bf(b[3]);
    return r.v;
}

// async global->LDS, 16B/lane: LDS dest = wave-uniform base + lane*16;
// global src is per-lane. __syncthreads() drains vmcnt before s_barrier.
__device__ __forceinline__ void gl_lds16(const void* g, void* l) {
    __builtin_amdgcn_global_load_lds(
        (const __attribute__((address_space(1))) unsigned int*)g,
        (__attribute__((address_space(3))) unsigned int*)l,
        16, 0, 0);
}

// ---------------------------------------------------------------------------
// 1) node_feats fp32 [4096][2048] -> bf16 (workspace), one pass
__global__ __launch_bounds__(256) void cvt_a(const float* __restrict__ in,
                                             unsigned short* __restrict__ out) {
    int tid = blockIdx.x * 256 + threadIdx.x;          // 2048*256 = 524288
    for (int p = tid; p < 2097152; p += 524288) {      // 8388608/4 float4s
        float4 v = *(const float4*)(in + (size_t)p * 4);
        ushort4 o;
        o.x = f2bf(v.x); o.y = f2bf(v.y); o.z = f2bf(v.z); o.w = f2bf(v.w);
        *(ushort4*)(out + (size_t)p * 4) = o;
    }
}

// ---------------------------------------------------------------------------
// 2) W_obj fp32 [2048][512] -> W_T bf16 [512][2048]  (tiled transpose)
__global__ __launch_bounds__(256) void cvt_bt(const float* __restrict__ W,
                                              unsigned short* __restrict__ WT) {
    __shared__ float lds[32][33];
    int k0 = blockIdx.x * 32, n0 = blockIdx.y * 32;
    int tx = threadIdx.x & 31, ty = threadIdx.x >> 5;  // ty 0..7
#pragma unroll
    for (int j = 0; j < 4; ++j)
        lds[ty + j * 8][tx] = W[(size_t)(k0 + ty + j * 8) * 512 + n0 + tx];
    __syncthreads();
#pragma unroll
    for (int j = 0; j < 4; ++j)
        WT[(size_t)(n0 + ty + j * 8) * 2048 + k0 + tx] = f2bf(lds[tx][ty + j * 8]);
}

// ---------------------------------------------------------------------------
// 3) GEMM1 (T3-minimum pipeline): node_h[4096][512](fp32)
//    = relu(A_bf16 @ W_T^T + b). BM=64 BN=64 BK=64, 256 thr (4 waves 2x2),
//    grid 512 = 2 blocks/CU. DOUBLE-BUFFERED linear LDS (32KB):
//      prologue: STAGE(buf0, s=0); barrier;
//      loop:     STAGE(buf^1, s+1);  MFMA(buf);  barrier;  flip.
//    The vmcnt(0) drain at the barrier lands one full compute-phase after
//    issue -> load latency hidden; 2 blocks/CU overlap the barrier tails.
__global__ __launch_bounds__(256) void gemm1(const unsigned short* __restrict__ A,
                                             const unsigned short* __restrict__ BT,
                                             const float* __restrict__ bias,
                                             float* __restrict__ C) {
    __shared__ __align__(16) unsigned short Asm[2][64 * 64];
    __shared__ __align__(16) unsigned short Bsm[2][64 * 64];

    // XCD swizzle: grid 512 (%8==0, bijective). per-XCD: 8 A m-panels
    // (2MB bf16) + full B (2MB) ~ L2-resident.
    int bid = blockIdx.x;
    int swz = (bid & 7) * 64 + (bid >> 3);
    int by = swz >> 3, bx = swz & 7;          // by 0..63, bx 0..7
    int m0 = by * 64, n0 = bx * 64;

    int t = threadIdx.x;
    int lane = t & 63, w = t >> 6;
    int wm = w >> 1, wn = w & 1;              // wave grid 2x2
    int l15 = lane & 15, l16 = lane >> 4;

    // staging: wave w covers A rows [w*16,w*16+16) and B rows [w*16,w*16+16),
    // 2 chunks each; chunk = 8 rows x 64 cols (1KB), lane l -> row l>>3,
    // cols (l&7)*8 => LDS byte off = l*16 (linear, matches gl_lds).
    int srow = lane >> 3, scol = (lane & 7) * 8;
    const unsigned short* aG = A  + (size_t)(m0 + w * 16 + srow) * 2048 + scol;
    const unsigned short* bG = BT + (size_t)(n0 + w * 16 + srow) * 2048 + scol;

    f32x4 acc[2][2];
#pragma unroll
    for (int i = 0; i < 2; ++i)
#pragma unroll
        for (int j = 0; j < 2; ++j) acc[i][j] = (f32x4){0.f, 0.f, 0.f, 0.f};

#define G1_STAGE(buf, step)                                                    \
    do {                                                                       \
        int _k0 = (step) * 64;                                                 \
        unsigned short* _aL = &Asm[buf][(w * 16) * 64];                        \
        unsigned short* _bL = &Bsm[buf][(w * 16) * 64];                        \
        gl_lds16(aG + _k0, _aL);                                               \
        gl_lds16(aG + (size_t)8 * 2048 + _k0, _aL + 8 * 64);                   \
        gl_lds16(bG + _k0, _bL);                                               \
        gl_lds16(bG + (size_t)8 * 2048 + _k0, _bL + 8 * 64);                   \
    } while (0)

    G1_STAGE(0, 0);
    __syncthreads();

    for (int s = 0; s < 32; ++s) {
        int cur = s & 1;
        if (s < 31) G1_STAGE(cur ^ 1, s + 1);   // issue next-tile loads first

        // compute from buf[cur]: 2 ksubs x (2x2) MFMAs
#pragma unroll
        for (int ks = 0; ks < 2; ++ks) {
            const unsigned short* ab = &Asm[cur][(wm * 32) * 64 + ks * 32 + l16 * 8];
            const unsigned short* bb = &Bsm[cur][(wn * 32) * 64 + ks * 32 + l16 * 8];
            bf16x8 a0 = *(const bf16x8*)(ab + (size_t)l15 * 64);
            bf16x8 a1 = *(const bf16x8*)(ab + (size_t)(16 + l15) * 64);
            bf16x8 b0 = *(const bf16x8*)(bb + (size_t)l15 * 64);
            bf16x8 b1 = *(const bf16x8*)(bb + (size_t)(16 + l15) * 64);
            acc[0][0] = __builtin_amdgcn_mfma_f32_16x16x32_bf16(a0, b0, acc[0][0], 0, 0, 0);
            acc[0][1] = __builtin_amdgcn_mfma_f32_16x16x32_bf16(a0, b1, acc[0][1], 0, 0, 0);
            acc[1][0] = __builtin_amdgcn_mfma_f32_16x16x32_bf16(a1, b0, acc[1][0], 0, 0, 0);
            acc[1][1] = __builtin_amdgcn_mfma_f32_16x16x32_bf16(a1, b1, acc[1][1], 0, 0, 0);
        }
        __syncthreads();   // drains vmcnt (next buf staged) + read-done fence
    }
#undef G1_STAGE

    // epilogue: bias + relu -> fp32; D layout col=lane&15, row=(lane>>4)*4+j
#pragma unroll
    for (int fm = 0; fm < 2; ++fm)
#pragma unroll
        for (int fn = 0; fn < 2; ++fn) {
            int col = n0 + wn * 32 + fn * 16 + l15;
            float bv = bias[col];
#pragma unroll
            for (int j = 0; j < 4; ++j) {
                int row = m0 + wm * 32 + fm * 16 + l16 * 4 + j;
                float v = acc[fm][fn][j] + bv;
                C[(size_t)row * 512 + col] = v > 0.f ? v : 0.f;
            }
        }
}

// ---------------------------------------------------------------------------
// 4) GEMM2 (fused fp32->bf16 MFMA, single-pass W_q):
//    part[z][64][4096] = q[64][k0:k0+128] @ W_q[k0:k0+128][c0:c0+128]
//    grid (32 colblocks, 8 ksplits) = 256 blocks x 256 thr (4 waves).
#define LDK2 136
__global__ __launch_bounds__(256) void gemm2(const float* __restrict__ qf,
                                             const float* __restrict__ Wq,
                                             float* __restrict__ part) {
    __shared__ __align__(16) unsigned short Asm[64][LDK2];   // q tile  [m][k]
    __shared__ __align__(16) unsigned short Bsm[128][LDK2];  // W tile  [c][k]

    int t = threadIdx.x;
    int lane = t & 63, w = t >> 6;          // 4 waves, wave owns 32 cols
    int l15 = lane & 15, l16 = lane >> 4;
    int c0 = blockIdx.x * 128;
    int k0 = blockIdx.y * 128;

    // ---- stage A: q[64][k0:k0+128] fp32 -> bf16 ----
#pragma unroll
    for (int j = 0; j < 4; ++j) {
        int g = t + j * 256;                 // 1024 chunks of 8k
        int row = g >> 4, kc = g & 15;
        const float* src = qf + (size_t)row * 1024 + k0 + kc * 8;
        f32x4 v0 = *(const f32x4*)(src);
        f32x4 v1 = *(const f32x4*)(src + 4);
        *(bf16x8*)(&Asm[row][kc * 8]) = pk8(v0, v1);
    }
    // ---- stage B: W_q[k0:k0+128][c0:c0+128] fp32 -> bf16, transposed ----
#pragma unroll
    for (int j = 0; j < 2; ++j) {
        int g = t + j * 256;                 // 512 units of 8k x 4c
        int kg = g >> 5, cg = g & 31;
        f32x4 wv[8];
#pragma unroll
        for (int kk = 0; kk < 8; ++kk)
            wv[kk] = *(const f32x4*)(Wq + (size_t)(k0 + kg * 8 + kk) * 4096 + c0 + cg * 4);
#pragma unroll
        for (int cc = 0; cc < 4; ++cc) {
            union { unsigned short us[8]; uint4 u4; } p;
#pragma unroll
            for (int kk = 0; kk < 8; ++kk) p.us[kk] = f2bf(wv[kk][cc]);
            *(uint4*)(&Bsm[cg * 4 + cc][kg * 8]) = p.u4;
        }
    }
    __syncthreads();

    // ---- MFMA: wave w covers cols [w*32, w*32+32); 4m x 2n x 4k frags ----
    f32x4 acc[4][2];
#pragma unroll
    for (int i = 0; i < 4; ++i)
#pragma unroll
        for (int j = 0; j < 2; ++j) acc[i][j] = (f32x4){0.f, 0.f, 0.f, 0.f};

#pragma unroll
    for (int ks = 0; ks < 4; ++ks) {
        bf16x8 bfr[2];
#pragma unroll
        for (int jn = 0; jn < 2; ++jn)
            bfr[jn] = *(const bf16x8*)(&Bsm[w * 32 + jn * 16 + l15][ks * 32 + l16 * 8]);
#pragma unroll
        for (int i = 0; i < 4; ++i) {
            bf16x8 afr = *(const bf16x8*)(&Asm[i * 16 + l15][ks * 32 + l16 * 8]);
            acc[i][0] = __builtin_amdgcn_mfma_f32_16x16x32_bf16(afr, bfr[0], acc[i][0], 0, 0, 0);
            acc[i][1] = __builtin_amdgcn_mfma_f32_16x16x32_bf16(afr, bfr[1], acc[i][1], 0, 0, 0);
        }
    }

    // ---- write partials ----
    float* pz = part + (size_t)blockIdx.y * 262144;
#pragma unroll
    for (int i = 0; i < 4; ++i)
#pragma unroll
        for (int jn = 0; jn < 2; ++jn) {
            int col = c0 + w * 32 + jn * 16 + l15;
#pragma unroll
            for (int j = 0; j < 4; ++j) {
                int row = i * 16 + l16 * 4 + j;
                pz[(size_t)row * 4096 + col] = acc[i][jn][j];
            }
        }
}

// ---------------------------------------------------------------------------
// 5) tail_k: one block per batch b (64 blocks x 256 thr = 4 waves).
//    Phase 1: q_h[b][*] = relu(sum_z part[z][b][*] + b_q)      -> LDS qs
//    Phase 2: inv_norm[b][k] = 1/sqrt(sum_h qs[h*8+k]^2)       -> LDS inv
//    Phase 3: P[n][k] = (node_h[b] @ q_e[b]) * inv             -> LDS Pl
//    Phase 4: out[m] = Pl[src] + Pl[dst] for the 512 edges of batch b
__global__ __launch_bounds__(256) void tail_k(const float* __restrict__ part,
                                              const float* __restrict__ bq,
                                              const float* __restrict__ node_h,
                                              const int* __restrict__ idxs,
                                              float* __restrict__ out) {
    __shared__ float qs[4096];
    __shared__ float red[4][8];
    __shared__ float inv[8];
    __shared__ float Pl[64][8];

    int b = blockIdx.x, t = threadIdx.x;
    int lane = t & 63, w = t >> 6;
    int l15 = lane & 15, l16 = lane >> 4;

    // ---- phase 1: reduce k-split partials + bias + relu ----
#pragma unroll
    for (int j = 0; j < 4; ++j) {
        int c = j * 1024 + t * 4;
        f32x4 a = (f32x4){0.f, 0.f, 0.f, 0.f};
#pragma unroll
        for (int z = 0; z < 8; ++z)
            a += *(const f32x4*)(part + (size_t)z * 262144 + (size_t)b * 4096 + c);
        f32x4 bb = *(const f32x4*)(bq + c);
#pragma unroll
        for (int i = 0; i < 4; ++i) {
            float v = a[i] + bb[i];
            a[i] = v > 0.f ? v : 0.f;
        }
        *(f32x4*)(&qs[c]) = a;
    }
    __syncthreads();

    // ---- phase 2: per-k norms ----
    {
        const float* row = qs + t * 16;
        float sq[8] = {0.f, 0.f, 0.f, 0.f, 0.f, 0.f, 0.f, 0.f};
#pragma unroll
        for (int j = 0; j < 4; ++j) {
            f32x4 v = *(const f32x4*)(row + j * 4);
            sq[(j * 4 + 0) & 7] += v[0] * v[0];
            sq[(j * 4 + 1) & 7] += v[1] * v[1];
            sq[(j * 4 + 2) & 7] += v[2] * v[2];
            sq[(j * 4 + 3) & 7] += v[3] * v[3];
        }
#pragma unroll
        for (int k = 0; k < 8; ++k) {
            float v = sq[k];
            v += __shfl_xor(v, 1);  v += __shfl_xor(v, 2);  v += __shfl_xor(v, 4);
            v += __shfl_xor(v, 8);  v += __shfl_xor(v, 16); v += __shfl_xor(v, 32);
            sq[k] = v;
        }
        if (lane == 0) {
#pragma unroll
            for (int k = 0; k < 8; ++k) red[w][k] = sq[k];
        }
    }
    __syncthreads();
    if (t < 8) {
        float s = red[0][t] + red[1][t] + red[2][t] + red[3][t];
        inv[t] = 1.0f / sqrtf(s);
    }
    __syncthreads();

    // ---- phase 3: P = (node_h[b] @ q_e) * inv  (MFMA 16x16x32, N=8 used) --
    {
        bool active = l15 < 8;
        float invv = active ? inv[l15] : 0.f;
        const float* arow = node_h + (size_t)(b * 64 + w * 16 + l15) * 512 + l16 * 8;
        f32x4 acc = (f32x4){0.f, 0.f, 0.f, 0.f};
#pragma unroll
        for (int kt = 0; kt < 16; ++kt) {
            f32x4 v0 = *(const f32x4*)(arow + kt * 32);
            f32x4 v1 = *(const f32x4*)(arow + kt * 32 + 4);
            bf16x8 af = pk8(v0, v1);
            union { unsigned short us[8]; bf16x8 v; } bqf;
#pragma unroll
            for (int i = 0; i < 8; ++i)
                bqf.us[i] = active ? f2bf(qs[kt * 256 + (l16 * 8 + i) * 8 + l15]) : 0;
            acc = __builtin_amdgcn_mfma_f32_16x16x32_bf16(af, bqf.v, acc, 0, 0, 0);
        }
        if (active) {
#pragma unroll
            for (int j = 0; j < 4; ++j)
                Pl[w * 16 + l16 * 4 + j][l15] = acc[j] * invv;
        }
    }
    __syncthreads();

    // ---- phase 4: 512 edges of batch b, 2 per thread ----
#pragma unroll
    for (int e = 0; e < 2; ++e) {
        int m = b * 512 + e * 256 + t;
        int idx = idxs[m];
        int r = idx & 4095;
        int src = r >> 6, dst = r & 63;
        f32x4 o0 = *(const f32x4*)(&Pl[src][0]) + *(const f32x4*)(&Pl[dst][0]);
        f32x4 o1 = *(const f32x4*)(&Pl[src][4]) + *(const f32x4*)(&Pl[dst][4]);
        *(f32x4*)(out + (size_t)m * 8)     = o0;
        *(f32x4*)(out + (size_t)m * 8 + 4) = o1;
    }
}

// ---------------------------------------------------------------------------
extern "C" void kernel_launch(void* const* d_in, const int* in_sizes, int n_in,
                              void* d_out, int out_size, void* d_ws, size_t ws_size,
                              hipStream_t stream) {
    const float* node_feats = (const float*)d_in[0];  // [64][64][2048]
    const float* q_feats    = (const float*)d_in[1];  // [64][1024]
    const int*   indexes    = (const int*)d_in[2];    // [32768]
    const float* W_obj      = (const float*)d_in[3];  // [2048][512]
    const float* b_obj      = (const float*)d_in[4];  // [512]
    const float* W_q        = (const float*)d_in[5];  // [1024][4096]
    const float* b_q        = (const float*)d_in[6];  // [4096]
    float* out = (float*)d_out;                       // [32768][8]

    char* ws = (char*)d_ws;
    unsigned short* A_bf16 = (unsigned short*)(ws + 0);        // 16.78MB
    unsigned short* W_T    = (unsigned short*)(ws + 16777216); // 2.10MB
    float* node_h          = (float*)(ws + 18874368);          // 8.39MB fp32
    float* part            = (float*)(ws + 0);                 // aliases A_bf16
                                                               // (gemm2 after gemm1)

    cvt_a<<<2048, 256, 0, stream>>>(node_feats, A_bf16);
    cvt_bt<<<dim3(64, 16), 256, 0, stream>>>(W_obj, W_T);
    gemm1<<<512, 256, 0, stream>>>(A_bf16, W_T, b_obj, node_h);
    gemm2<<<dim3(32, 8), 256, 0, stream>>>(q_feats, W_q, part);
    tail_k<<<64, 256, 0, stream>>>(part, b_q, node_h, indexes, out);
}

// Round 10
// 43.180 us; speedup vs baseline: 1.8840x; 1.6345x over previous
//
#include <hip/hip_runtime.h>
#include <hip/hip_bf16.h>

// Problem constants (EdgeQProj): B=64, N=64, E=512, OBJ_DIM=2048, Q_DIM=1024,
// HID=512, KS=8. M_edges = B*E = 32768.
//
// Pipeline (identity: edge_logit[m] = P[b,src]+P[b,dst]):
//   cvt_k     : node_feats -> A_bf16 (SWIZZLED), W_obj -> W_T bf16 (SWIZZLED)
//   gemm_fused: blocks 0-255 = gemm2 (q partials), 256-767 = gemm1 (node_h)
//   tail_k    : per-batch reduce+bias+relu -> norms -> P-MFMA -> edges
//
// Swizzle (rule #21, both-sides): within each 128-elem (256B) k-chunk of a
// row, 16B slot g holds data of slot g ^ (row&15). gl_lds copies linearly;
// gemm1's ds_read applies the same XOR -> 64 lanes spread over all 32 banks.

using bf16x8 = __attribute__((ext_vector_type(8))) __bf16;
using f32x4  = __attribute__((ext_vector_type(4))) float;

__device__ __forceinline__ unsigned short f2bf(float f) {
    unsigned int u = __float_as_uint(f);
    unsigned int r = (u + 0x7FFFu + ((u >> 16) & 1u)) >> 16;  // RNE
    return (unsigned short)r;
}

__device__ __forceinline__ uint4 pk8u(f32x4 a, f32x4 b) {
    union { unsigned short us[8]; uint4 u4; } r;
    r.us[0] = f2bf(a[0]); r.us[1] = f2bf(a[1]); r.us[2] = f2bf(a[2]); r.us[3] = f2bf(a[3]);
    r.us[4] = f2bf(b[0]); r.us[5] = f2bf(b[1]); r.us[6] = f2bf(b[2]); r.us[7] = f2bf(b[3]);
    return r.u4;
}

__device__ __forceinline__ bf16x8 pk8(f32x4 a, f32x4 b) {
    union { uint4 u4; bf16x8 v; } r;
    r.u4 = pk8u(a, b);
    return r.v;
}

__device__ __forceinline__ void gl_lds16(const void* g, void* l) {
    __builtin_amdgcn_global_load_lds(
        (const __attribute__((address_space(1))) unsigned int*)g,
        (__attribute__((address_space(3))) unsigned int*)l,
        16, 0, 0);
}

// ---------------------------------------------------------------------------
// 1) merged converts. blocks 0..2047: node_feats -> A_swz bf16 (row-chunk
//    swizzled). blocks 2048..3071: W_obj -> W_T bf16 transposed + swizzled.
__global__ __launch_bounds__(256) void cvt_k(const float* __restrict__ nf,
                                             const float* __restrict__ W,
                                             unsigned short* __restrict__ A,
                                             unsigned short* __restrict__ WT) {
    __shared__ float lds[32][33];
    int bid = blockIdx.x;
    if (bid < 2048) {
        // ---- A convert+swizzle: thread handles 16B-out groups ----
        int tid = bid * 256 + threadIdx.x;            // 524288 threads
        for (int p = tid; p < 1048576; p += 524288) { // 8-elem groups
            int r = p >> 8;                           // row 0..4095
            int grp = p & 255;                        // group within row
            int chunk = grp >> 4, slot = grp & 15;
            int sslot = slot ^ (r & 15);
            const float* src = nf + (size_t)r * 2048 + chunk * 128 + sslot * 8;
            f32x4 v0 = *(const f32x4*)(src);
            f32x4 v1 = *(const f32x4*)(src + 4);
            *(uint4*)(A + (size_t)r * 2048 + chunk * 128 + slot * 8) = pk8u(v0, v1);
        }
    } else {
        // ---- W_T transpose + convert + swizzle ----
        int g = bid - 2048;                           // 0..1023
        int k0 = (g & 63) * 32, n0 = (g >> 6) * 32;
        int tx = threadIdx.x & 31, ty = threadIdx.x >> 5;
#pragma unroll
        for (int j = 0; j < 4; ++j)
            lds[ty + j * 8][tx] = W[(size_t)(k0 + ty + j * 8) * 512 + n0 + tx];
        __syncthreads();
#pragma unroll
        for (int j = 0; j < 4; ++j) {
            int n = n0 + ty + j * 8;
            int k = k0 + tx;
            int chunk = k >> 7, off = k & 127;
            int ksw = chunk * 128 + (((off >> 3) ^ (n & 15)) << 3) + (off & 7);
            WT[(size_t)n * 2048 + ksw] = f2bf(lds[tx][ty + j * 8]);
        }
    }
}

// ---------------------------------------------------------------------------
// gemm1 body: node_h[4096][512](fp32) = relu(A_swz @ W_T^T + b).
// BM=64 BN=64 BK=128, 256 thr (4 waves 2x2 of 32x32), grid 512 = 2/CU.
// Double-buffered gl_lds LDS (64KB). Swizzled ds_read (conflict-optimal).
__device__ __forceinline__ void gemm1_body(char* smem, int g1, int t,
                                           const unsigned short* __restrict__ A,
                                           const unsigned short* __restrict__ BT,
                                           const float* __restrict__ bias,
                                           float* __restrict__ C) {
    unsigned short* AsmB = (unsigned short*)smem;            // [2][64][128]
    unsigned short* BsmB = (unsigned short*)(smem + 32768);  // [2][64][128]

    // XCD swizzle over 512 gemm1-blocks (bijective).
    int swz = (g1 & 7) * 64 + (g1 >> 3);
    int by = swz >> 3, bx = swz & 7;
    int m0 = by * 64, n0 = bx * 64;

    int lane = t & 63, w = t >> 6;
    int wm = w >> 1, wn = w & 1;              // wave grid 2x2
    int l15 = lane & 15, l16 = lane >> 4;

    // staging: wave w owns A rows [w*16,w*16+16) and B rows same; chunk =
    // 4 rows x 256B; lane l -> row l>>4, 16B slot l&15 (linear = gl_lds).
    int srow = lane >> 4, scol = (lane & 15) * 8;
    const unsigned short* aG = A  + (size_t)(m0 + w * 16 + srow) * 2048 + scol;
    const unsigned short* bG = BT + (size_t)(n0 + w * 16 + srow) * 2048 + scol;

    f32x4 acc[2][2];
#pragma unroll
    for (int i = 0; i < 2; ++i)
#pragma unroll
        for (int j = 0; j < 2; ++j) acc[i][j] = (f32x4){0.f, 0.f, 0.f, 0.f};

#define G1_STAGE(buf, step)                                                    \
    do {                                                                       \
        int _ko = (step) * 128;                                                \
        unsigned short* _aL = AsmB + (buf) * 8192 + (w * 16) * 128;            \
        unsigned short* _bL = BsmB + (buf) * 8192 + (w * 16) * 128;            \
        _Pragma("unroll")                                                      \
        for (int _i = 0; _i < 4; ++_i) {                                       \
            gl_lds16(aG + (size_t)(_i * 4) * 2048 + _ko, _aL + (_i * 4) * 128);\
            gl_lds16(bG + (size_t)(_i * 4) * 2048 + _ko, _bL + (_i * 4) * 128);\
        }                                                                      \
    } while (0)

    G1_STAGE(0, 0);
    __syncthreads();

    for (int s = 0; s < 16; ++s) {
        int cur = s & 1;
        if (s < 15) G1_STAGE(cur ^ 1, s + 1);   // issue next-tile loads first

        const char* Ab = (const char*)(AsmB + cur * 8192);
        const char* Bb = (const char*)(BsmB + cur * 8192);
#pragma unroll
        for (int ks = 0; ks < 4; ++ks) {
            int co = ks * 64 + l16 * 16;        // byte col within 256B row
            int r0 = wm * 32 + l15, r1 = r0 + 16;
            int c0n = wn * 32 + l15, c1n = c0n + 16;
            bf16x8 a0 = *(const bf16x8*)(Ab + r0 * 256 + (co ^ ((r0 & 15) << 4)));
            bf16x8 a1 = *(const bf16x8*)(Ab + r1 * 256 + (co ^ ((r1 & 15) << 4)));
            bf16x8 b0 = *(const bf16x8*)(Bb + c0n * 256 + (co ^ ((c0n & 15) << 4)));
            bf16x8 b1 = *(const bf16x8*)(Bb + c1n * 256 + (co ^ ((c1n & 15) << 4)));
            acc[0][0] = __builtin_amdgcn_mfma_f32_16x16x32_bf16(a0, b0, acc[0][0], 0, 0, 0);
            acc[0][1] = __builtin_amdgcn_mfma_f32_16x16x32_bf16(a0, b1, acc[0][1], 0, 0, 0);
            acc[1][0] = __builtin_amdgcn_mfma_f32_16x16x32_bf16(a1, b0, acc[1][0], 0, 0, 0);
            acc[1][1] = __builtin_amdgcn_mfma_f32_16x16x32_bf16(a1, b1, acc[1][1], 0, 0, 0);
        }
        __syncthreads();
    }
#undef G1_STAGE

    // epilogue: bias + relu -> fp32; D layout col=lane&15, row=(lane>>4)*4+j
#pragma unroll
    for (int fm = 0; fm < 2; ++fm)
#pragma unroll
        for (int fn = 0; fn < 2; ++fn) {
            int col = n0 + wn * 32 + fn * 16 + l15;
            float bv = bias[col];
#pragma unroll
            for (int j = 0; j < 4; ++j) {
                int row = m0 + wm * 32 + fm * 16 + l16 * 4 + j;
                float v = acc[fm][fn][j] + bv;
                C[(size_t)row * 512 + col] = v > 0.f ? v : 0.f;
            }
        }
}

// ---------------------------------------------------------------------------
// gemm2 body (unchanged math): part[z][64][4096], single-pass W_q.
#define LDK2 136
__device__ __forceinline__ void gemm2_body(char* smem, int bid2, int t,
                                           const float* __restrict__ qf,
                                           const float* __restrict__ Wq,
                                           float* __restrict__ part) {
    auto Asm = reinterpret_cast<unsigned short(*)[LDK2]>(smem);              // [64][136]
    auto Bsm = reinterpret_cast<unsigned short(*)[LDK2]>(smem + 64 * LDK2 * 2); // [128][136]

    int lane = t & 63, w = t >> 6;
    int l15 = lane & 15, l16 = lane >> 4;
    int c0 = (bid2 & 31) * 128;
    int k0 = (bid2 >> 5) * 128;

#pragma unroll
    for (int j = 0; j < 4; ++j) {
        int g = t + j * 256;
        int row = g >> 4, kc = g & 15;
        const float* src = qf + (size_t)row * 1024 + k0 + kc * 8;
        f32x4 v0 = *(const f32x4*)(src);
        f32x4 v1 = *(const f32x4*)(src + 4);
        *(uint4*)(&Asm[row][kc * 8]) = pk8u(v0, v1);
    }
#pragma unroll
    for (int j = 0; j < 2; ++j) {
        int g = t + j * 256;
        int kg = g >> 5, cg = g & 31;
        f32x4 wv[8];
#pragma unroll
        for (int kk = 0; kk < 8; ++kk)
            wv[kk] = *(const f32x4*)(Wq + (size_t)(k0 + kg * 8 + kk) * 4096 + c0 + cg * 4);
#pragma unroll
        for (int cc = 0; cc < 4; ++cc) {
            union { unsigned short us[8]; uint4 u4; } p;
#pragma unroll
            for (int kk = 0; kk < 8; ++kk) p.us[kk] = f2bf(wv[kk][cc]);
            *(uint4*)(&Bsm[cg * 4 + cc][kg * 8]) = p.u4;
        }
    }
    __syncthreads();

    f32x4 acc[4][2];
#pragma unroll
    for (int i = 0; i < 4; ++i)
#pragma unroll
        for (int j = 0; j < 2; ++j) acc[i][j] = (f32x4){0.f, 0.f, 0.f, 0.f};

#pragma unroll
    for (int ks = 0; ks < 4; ++ks) {
        bf16x8 bfr[2];
#pragma unroll
        for (int jn = 0; jn < 2; ++jn)
            bfr[jn] = *(const bf16x8*)(&Bsm[w * 32 + jn * 16 + l15][ks * 32 + l16 * 8]);
#pragma unroll
        for (int i = 0; i < 4; ++i) {
            bf16x8 afr = *(const bf16x8*)(&Asm[i * 16 + l15][ks * 32 + l16 * 8]);
            acc[i][0] = __builtin_amdgcn_mfma_f32_16x16x32_bf16(afr, bfr[0], acc[i][0], 0, 0, 0);
            acc[i][1] = __builtin_amdgcn_mfma_f32_16x16x32_bf16(afr, bfr[1], acc[i][1], 0, 0, 0);
        }
    }

    float* pz = part + (size_t)(bid2 >> 5) * 262144;
#pragma unroll
    for (int i = 0; i < 4; ++i)
#pragma unroll
        for (int jn = 0; jn < 2; ++jn) {
            int col = c0 + w * 32 + jn * 16 + l15;
#pragma unroll
            for (int j = 0; j < 4; ++j) {
                int row = i * 16 + l16 * 4 + j;
                pz[(size_t)row * 4096 + col] = acc[i][jn][j];
            }
        }
}

// ---------------------------------------------------------------------------
// 2) fused: blocks 0..255 gemm2, 256..767 gemm1 (concurrent, no aliasing).
__global__ __launch_bounds__(256) void gemm_fused(const unsigned short* A,
                                                  const unsigned short* BT,
                                                  const float* bias, float* C,
                                                  const float* qf, const float* Wq,
                                                  float* part) {
    __shared__ __align__(16) char smem[65536];
    int bid = blockIdx.x, t = threadIdx.x;
    if (bid < 256) gemm2_body(smem, bid, t, qf, Wq, part);
    else           gemm1_body(smem, bid - 256, t, A, BT, bias, C);
}
// fallback wrappers (sequential path if ws too small for un-aliased part)
__global__ __launch_bounds__(256) void gemm1_only(const unsigned short* A,
                                                  const unsigned short* BT,
                                                  const float* bias, float* C) {
    __shared__ __align__(16) char smem[65536];
    gemm1_body(smem, blockIdx.x, threadIdx.x, A, BT, bias, C);
}
__global__ __launch_bounds__(256) void gemm2_only(const float* qf, const float* Wq,
                                                  float* part) {
    __shared__ __align__(16) char smem[65536];
    gemm2_body(smem, blockIdx.x, threadIdx.x, qf, Wq, part);
}

// ---------------------------------------------------------------------------
// 3) tail_k: one block per batch (64 x 256 thr). reduce+bias+relu -> norms ->
//    P-MFMA -> 512 edge gather-adds.
__global__ __launch_bounds__(256) void tail_k(const float* __restrict__ part,
                                              const float* __restrict__ bq,
                                              const float* __restrict__ node_h,
                                              const int* __restrict__ idxs,
                                              float* __restrict__ out) {
    __shared__ float qs[4096];
    __shared__ float red[4][8];
    __shared__ float inv[8];
    __shared__ float Pl[64][8];

    int b = blockIdx.x, t = threadIdx.x;
    int lane = t & 63, w = t >> 6;
    int l15 = lane & 15, l16 = lane >> 4;

#pragma unroll
    for (int j = 0; j < 4; ++j) {
        int c = j * 1024 + t * 4;
        f32x4 a = (f32x4){0.f, 0.f, 0.f, 0.f};
#pragma unroll
        for (int z = 0; z < 8; ++z)
            a += *(const f32x4*)(part + (size_t)z * 262144 + (size_t)b * 4096 + c);
        f32x4 bb = *(const f32x4*)(bq + c);
#pragma unroll
        for (int i = 0; i < 4; ++i) {
            float v = a[i] + bb[i];
            a[i] = v > 0.f ? v : 0.f;
        }
        *(f32x4*)(&qs[c]) = a;
    }
    __syncthreads();

    {
        const float* row = qs + t * 16;
        float sq[8] = {0.f, 0.f, 0.f, 0.f, 0.f, 0.f, 0.f, 0.f};
#pragma unroll
        for (int j = 0; j < 4; ++j) {
            f32x4 v = *(const f32x4*)(row + j * 4);
            sq[(j * 4 + 0) & 7] += v[0] * v[0];
            sq[(j * 4 + 1) & 7] += v[1] * v[1];
            sq[(j * 4 + 2) & 7] += v[2] * v[2];
            sq[(j * 4 + 3) & 7] += v[3] * v[3];
        }
#pragma unroll
        for (int k = 0; k < 8; ++k) {
            float v = sq[k];
            v += __shfl_xor(v, 1);  v += __shfl_xor(v, 2);  v += __shfl_xor(v, 4);
            v += __shfl_xor(v, 8);  v += __shfl_xor(v, 16); v += __shfl_xor(v, 32);
            sq[k] = v;
        }
        if (lane == 0) {
#pragma unroll
            for (int k = 0; k < 8; ++k) red[w][k] = sq[k];
        }
    }
    __syncthreads();
    if (t < 8) {
        float s = red[0][t] + red[1][t] + red[2][t] + red[3][t];
        inv[t] = 1.0f / sqrtf(s);
    }
    __syncthreads();

    {
        bool active = l15 < 8;
        float invv = active ? inv[l15] : 0.f;
        const float* arow = node_h + (size_t)(b * 64 + w * 16 + l15) * 512 + l16 * 8;
        f32x4 acc = (f32x4){0.f, 0.f, 0.f, 0.f};
#pragma unroll
        for (int kt = 0; kt < 16; ++kt) {
            f32x4 v0 = *(const f32x4*)(arow + kt * 32);
            f32x4 v1 = *(const f32x4*)(arow + kt * 32 + 4);
            bf16x8 af = pk8(v0, v1);
            union { unsigned short us[8]; bf16x8 v; } bqf;
#pragma unroll
            for (int i = 0; i < 8; ++i)
                bqf.us[i] = active ? f2bf(qs[kt * 256 + (l16 * 8 + i) * 8 + l15]) : 0;
            acc = __builtin_amdgcn_mfma_f32_16x16x32_bf16(af, bqf.v, acc, 0, 0, 0);
        }
        if (active) {
#pragma unroll
            for (int j = 0; j < 4; ++j)
                Pl[w * 16 + l16 * 4 + j][l15] = acc[j] * invv;
        }
    }
    __syncthreads();

#pragma unroll
    for (int e = 0; e < 2; ++e) {
        int m = b * 512 + e * 256 + t;
        int idx = idxs[m];
        int r = idx & 4095;
        int src = r >> 6, dst = r & 63;
        f32x4 o0 = *(const f32x4*)(&Pl[src][0]) + *(const f32x4*)(&Pl[dst][0]);
        f32x4 o1 = *(const f32x4*)(&Pl[src][4]) + *(const f32x4*)(&Pl[dst][4]);
        *(f32x4*)(out + (size_t)m * 8)     = o0;
        *(f32x4*)(out + (size_t)m * 8 + 4) = o1;
    }
}

// ---------------------------------------------------------------------------
extern "C" void kernel_launch(void* const* d_in, const int* in_sizes, int n_in,
                              void* d_out, int out_size, void* d_ws, size_t ws_size,
                              hipStream_t stream) {
    const float* node_feats = (const float*)d_in[0];  // [64][64][2048]
    const float* q_feats    = (const float*)d_in[1];  // [64][1024]
    const int*   indexes    = (const int*)d_in[2];    // [32768]
    const float* W_obj      = (const float*)d_in[3];  // [2048][512]
    const float* b_obj      = (const float*)d_in[4];  // [512]
    const float* W_q        = (const float*)d_in[5];  // [1024][4096]
    const float* b_q        = (const float*)d_in[6];  // [4096]
    float* out = (float*)d_out;                       // [32768][8]

    char* ws = (char*)d_ws;
    unsigned short* A_swz = (unsigned short*)(ws + 0);         // 16.78MB
    unsigned short* W_T   = (unsigned short*)(ws + 16777216);  // 2.10MB
    float* node_h         = (float*)(ws + 18874368);           // 8.39MB

    if (ws_size >= 35651584ull) {
        // concurrent layout: part has its own region (no aliasing with A_swz)
        float* part = (float*)(ws + 27262976);                 // 8.39MB
        cvt_k<<<3072, 256, 0, stream>>>(node_feats, W_obj, A_swz, W_T);
        gemm_fused<<<768, 256, 0, stream>>>(A_swz, W_T, b_obj, node_h,
                                            q_feats, W_q, part);
        tail_k<<<64, 256, 0, stream>>>(part, b_q, node_h, indexes, out);
    } else {
        // sequential fallback: part aliases A_swz (gemm2 after gemm1)
        float* part = (float*)(ws + 0);
        cvt_k<<<3072, 256, 0, stream>>>(node_feats, W_obj, A_swz, W_T);
        gemm1_only<<<512, 256, 0, stream>>>(A_swz, W_T, b_obj, node_h);
        gemm2_only<<<256, 256, 0, stream>>>(q_feats, W_q, part);
        tail_k<<<64, 256, 0, stream>>>(part, b_q, node_h, indexes, out);
    }
}